// Round 2
// baseline (355.402 us; speedup 1.0000x reference)
//
#include <hip/hip_runtime.h>
#include <math.h>

#define BATCH 64
#define ADIM  1152
#define BDIM  32
#define POSE  16
#define SLICE 512                    // BDIM*POSE floats per (batch) capsule-state
#define CHUNKS 16
#define A_PER_CHUNK 72               // 1152/16
#define STEPS 9                      // 72 rows / 8 rows-per-step
#define EPSQ 1e-6f

// One pass over v for routing iteration `iter`:
//   b[a,bc] = logits[a,bc] + sum_{j<iter} dot(p_j[bc,:], v[a,bc,:])
//   c[a,:]  = softmax_bc(b[a,:])
//   s[bc,k] += sum_a c[a,bc] * v[a,bc,k]
// v is staged global->reg->LDS (XOR-swizzled) so global loads are fully
// coalesced (4 KB contiguous per wave-instr) and LDS reads spread banks.
__global__ __launch_bounds__(256, 4) void route_pass(
    const float* __restrict__ v,       // [BATCH][ADIM][BDIM][POSE]
    const float* __restrict__ logits,  // [ADIM][BDIM]
    const float* __restrict__ p_buf,   // [3][BATCH][SLICE]
    float* __restrict__ s_out,         // [BATCH][SLICE] (this iter's slice)
    int iter)
{
    const int bt    = blockIdx.x / CHUNKS;
    const int chunk = blockIdx.x % CHUNKS;
    const int t     = threadIdx.x;
    const int bc    = t & 31;   // capsule (softmax dim)
    const int a_sub = t >> 5;   // row within the 8-row step

    __shared__ __align__(16) float smem[8 * SLICE];  // 16 KB: staging tile, then reduce scratch
    float4* tile = (float4*)smem;

    // loop-invariant p fragments in registers (kills LDS bank conflicts on the dot)
    float p0[POSE], p1[POSE];
    if (iter >= 1) {
        const float4* pp = (const float4*)(p_buf + (size_t)bt * SLICE + bc * POSE);
#pragma unroll
        for (int q = 0; q < 4; ++q) {
            float4 f = pp[q];
            p0[4*q+0]=f.x; p0[4*q+1]=f.y; p0[4*q+2]=f.z; p0[4*q+3]=f.w;
        }
    }
    if (iter >= 2) {
        const float4* pp = (const float4*)(p_buf + (size_t)(BATCH + bt) * SLICE + bc * POSE);
#pragma unroll
        for (int q = 0; q < 4; ++q) {
            float4 f = pp[q];
            p1[4*q+0]=f.x; p1[4*q+1]=f.y; p1[4*q+2]=f.z; p1[4*q+3]=f.w;
        }
    }

    float acc[POSE];
#pragma unroll
    for (int k = 0; k < POSE; ++k) acc[k] = 0.f;

    const int a0 = chunk * A_PER_CHUNK;
    const float4* gbase = (const float4*)(v + ((size_t)bt * ADIM + a0) * SLICE);

    // prefetch step 0 (8 rows = 1024 float4s, 4 per thread, contiguous)
    float4 r[4];
#pragma unroll
    for (int i = 0; i < 4; ++i) r[i] = gbase[t + 256 * i];

    for (int step = 0; step < STEPS; ++step) {
        // store staged regs to LDS, XOR-swizzled within each 128-f4 row
#pragma unroll
        for (int i = 0; i < 4; ++i) {
            int L   = t + 256 * i;
            int row = L >> 7;
            int col = L & 127;
            tile[row * 128 + (col ^ ((col >> 2) & 7))] = r[i];
        }
        __syncthreads();

        if (step + 1 < STEPS) {
            const float4* gnext = gbase + (size_t)(step + 1) * 1024;
#pragma unroll
            for (int i = 0; i < 4; ++i) r[i] = gnext[t + 256 * i];
        }

        // compute: this thread owns (a = a0 + step*8 + a_sub, bc)
        float vv[POSE];
#pragma unroll
        for (int q = 0; q < 4; ++q) {
            float4 f = tile[a_sub * 128 + ((bc * 4 + q) ^ (bc & 7))];
            vv[4*q+0]=f.x; vv[4*q+1]=f.y; vv[4*q+2]=f.z; vv[4*q+3]=f.w;
        }

        const int a = a0 + step * 8 + a_sub;
        float bval = logits[a * BDIM + bc];
        if (iter >= 1) {
            float d = 0.f;
#pragma unroll
            for (int k = 0; k < POSE; ++k) d = fmaf(p0[k], vv[k], d);
            bval += d;
        }
        if (iter >= 2) {
            float d = 0.f;
#pragma unroll
            for (int k = 0; k < POSE; ++k) d = fmaf(p1[k], vv[k], d);
            bval += d;
        }

        // softmax over the 32 capsules (32-lane shuffle groups inside wave64)
        float m = bval;
#pragma unroll
        for (int off = 16; off > 0; off >>= 1)
            m = fmaxf(m, __shfl_xor(m, off, 32));
        float e = __expf(bval - m);
        float ssum = e;
#pragma unroll
        for (int off = 16; off > 0; off >>= 1)
            ssum += __shfl_xor(ssum, off, 32);
        float c = e / ssum;

#pragma unroll
        for (int k = 0; k < POSE; ++k) acc[k] = fmaf(c, vv[k], acc[k]);
        __syncthreads();
    }

    // reduce the 8 a_sub partials in LDS (tile reuse), one atomicAdd per element
    float* red = smem;
#pragma unroll
    for (int k = 0; k < POSE; ++k) red[a_sub * SLICE + bc * POSE + k] = acc[k];
    __syncthreads();

    for (int idx = t; idx < SLICE; idx += 256) {
        float s = 0.f;
#pragma unroll
        for (int asb = 0; asb < 8; ++asb) s += red[asb * SLICE + idx];
        atomicAdd(&s_out[(size_t)bt * SLICE + idx], s);
    }
}

// squash: norm_sq over the B dim per pose element; last iter also emits outputs
__global__ __launch_bounds__(512) void squash_kernel(
    const float* __restrict__ s_in,   // [BATCH][SLICE]
    float* __restrict__ p_out,        // [BATCH][SLICE]
    float* __restrict__ out,          // a_out (8192) ++ p (32768)
    int last)
{
    const int bt = blockIdx.x;
    const int t = threadIdx.x;        // t = bc*16 + pose
    const int pose = t & 15;

    __shared__ float sq[512];
    __shared__ float ns[16];

    float sv = s_in[(size_t)bt * SLICE + t];
    sq[t] = sv * sv;
    __syncthreads();
    if (t < 16) {
        float a = 0.f;
        for (int b2 = 0; b2 < BDIM; ++b2) a += sq[b2 * POSE + t];
        ns[t] = a;
    }
    __syncthreads();
    float n = ns[pose];
    float pv = sqrtf(n + EPSQ) / (1.f + n) * sv;
    p_out[(size_t)bt * SLICE + t] = pv;

    if (last) {
        out[8192 + bt * SLICE + t] = pv;
        sq[t] = pv * pv;
        __syncthreads();
        // a_out[bt][bc][p2] = sqrt(sum_p1 p[bc][p1][p2]^2)
        if (t < 128) {
            int b2 = t >> 2, p2 = t & 3;
            float a = 0.f;
#pragma unroll
            for (int p1 = 0; p1 < 4; ++p1) a += sq[b2 * POSE + p1 * 4 + p2];
            out[bt * 128 + b2 * 4 + p2] = sqrtf(a);
        }
    }
}

extern "C" void kernel_launch(void* const* d_in, const int* in_sizes, int n_in,
                              void* d_out, int out_size, void* d_ws, size_t ws_size,
                              hipStream_t stream) {
    const float* v      = (const float*)d_in[1];   // (64,1152,32,4,4,1)
    const float* logits = (const float*)d_in[2];   // (1,1152,32,1,1,1)
    float* out = (float*)d_out;

    // workspace: 3 s-buffers + 3 p-buffers, each [BATCH][SLICE] fp32 (768 KB)
    float* s_buf = (float*)d_ws;
    float* p_buf = s_buf + 3 * BATCH * SLICE;

    hipMemsetAsync(s_buf, 0, (size_t)3 * BATCH * SLICE * sizeof(float), stream);

    for (int it = 0; it < 3; ++it) {
        route_pass<<<dim3(BATCH * CHUNKS), dim3(256), 0, stream>>>(
            v, logits, p_buf, s_buf + (size_t)it * BATCH * SLICE, it);
        squash_kernel<<<dim3(BATCH), dim3(512), 0, stream>>>(
            s_buf + (size_t)it * BATCH * SLICE,
            p_buf + (size_t)it * BATCH * SLICE,
            out, it == 2 ? 1 : 0);
    }
}

// Round 3
// 275.617 us; speedup vs baseline: 1.2895x; 1.2895x over previous
//
#include <hip/hip_runtime.h>
#include <math.h>

#define BATCH 64
#define ADIM  1152
#define BDIM  32
#define POSE  16
#define SLICE 512                    // BDIM*POSE floats per batch capsule-state
#define CHUNKS 16
#define A_PER_CHUNK 72               // 1152/16
#define STEPS 9                      // 72 rows / 8 rows-per-step
#define EPSQ 1e-6f
#define SPART_ITER ((size_t)BATCH * CHUNKS * SLICE)   // floats per iter of s_part

// s_part layout: [iter][bt][chunk][SLICE]  (deterministic partials, no atomics)
//
// route_pass<ITER>:
//   prologue: p_j (j<ITER) rebuilt per-block from s_part[j] (chunk-reduce+squash)
//   main:     b = logits + sum_j p_j.v ; c = softmax_bc(b) ; partial s = sum_a c*v
// v staged global->reg->LDS (XOR swizzle): global loads fully coalesced,
// LDS b128 reads spread uniformly over bank groups.
template<int ITER>
__global__ __launch_bounds__(256) void route_pass(
    const float* __restrict__ v,       // [BATCH][ADIM][BDIM][POSE]
    const float* __restrict__ logits,  // [ADIM][BDIM]
    const float* __restrict__ s_part,  // base (reads iters < ITER)
    float* __restrict__ s_out)         // [bt][chunk][SLICE] for this iter
{
    const int bt    = blockIdx.x / CHUNKS;
    const int chunk = blockIdx.x % CHUNKS;
    const int t     = threadIdx.x;
    const int bc    = t & 31;   // capsule (softmax dim)
    const int a_sub = t >> 5;   // row within the 8-row step

    __shared__ __align__(16) float smem[8 * SLICE];  // 16 KB tile / reduce scratch
    __shared__ float sred[SLICE];
    __shared__ float fac[POSE];
    float4* tile = (float4*)smem;

    // ---- prologue: reconstruct p_j for j < ITER (registers, per-thread bc) ----
    float p0[POSE], p1[POSE];
#pragma unroll
    for (int j = 0; j < ITER; ++j) {
        for (int e = t; e < SLICE; e += 256) {
            const float* sp = s_part + (size_t)j * SPART_ITER
                            + (size_t)bt * CHUNKS * SLICE + e;
            float s = 0.f;
#pragma unroll
            for (int c = 0; c < CHUNKS; ++c) s += sp[c * SLICE];
            sred[e] = s;
        }
        __syncthreads();
        if (t < POSE) {
            float ns = 0.f;
            for (int b2 = 0; b2 < BDIM; ++b2) {
                float x = sred[b2 * POSE + t];
                ns += x * x;
            }
            fac[t] = sqrtf(ns + EPSQ) / (1.f + ns);
        }
        __syncthreads();
#pragma unroll
        for (int k = 0; k < POSE; ++k) {
            float pv = fac[k] * sred[bc * POSE + k];
            if (j == 0) p0[k] = pv; else p1[k] = pv;
        }
        __syncthreads();
    }

    float acc[POSE];
#pragma unroll
    for (int k = 0; k < POSE; ++k) acc[k] = 0.f;

    const int a0 = chunk * A_PER_CHUNK;
    const float4* gbase = (const float4*)(v + ((size_t)bt * ADIM + a0) * SLICE);

    // prefetch step 0 (8 rows = 1024 float4s, 4 per thread, contiguous)
    float4 r0 = gbase[t];
    float4 r1 = gbase[t + 256];
    float4 r2 = gbase[t + 512];
    float4 r3 = gbase[t + 768];

    for (int step = 0; step < STEPS; ++step) {
        // store staged regs to LDS, XOR-swizzled within each 128-f4 row
        {
            int L, row, col;
            L = t;        row = L >> 7; col = L & 127; tile[row*128 + (col ^ ((col>>2)&7))] = r0;
            L = t + 256;  row = L >> 7; col = L & 127; tile[row*128 + (col ^ ((col>>2)&7))] = r1;
            L = t + 512;  row = L >> 7; col = L & 127; tile[row*128 + (col ^ ((col>>2)&7))] = r2;
            L = t + 768;  row = L >> 7; col = L & 127; tile[row*128 + (col ^ ((col>>2)&7))] = r3;
        }
        __syncthreads();

        if (step + 1 < STEPS) {
            const float4* gnext = gbase + (size_t)(step + 1) * 1024;
            r0 = gnext[t];
            r1 = gnext[t + 256];
            r2 = gnext[t + 512];
            r3 = gnext[t + 768];
        }

        // compute: this thread owns (a = a0 + step*8 + a_sub, bc)
        float vv[POSE];
#pragma unroll
        for (int q = 0; q < 4; ++q) {
            float4 f = tile[a_sub * 128 + ((bc * 4 + q) ^ (bc & 7))];
            vv[4*q+0] = f.x; vv[4*q+1] = f.y; vv[4*q+2] = f.z; vv[4*q+3] = f.w;
        }

        const int a = a0 + step * 8 + a_sub;
        float bval = logits[a * BDIM + bc];
        if (ITER >= 1) {
            float d = 0.f;
#pragma unroll
            for (int k = 0; k < POSE; ++k) d = fmaf(p0[k], vv[k], d);
            bval += d;
        }
        if (ITER >= 2) {
            float d = 0.f;
#pragma unroll
            for (int k = 0; k < POSE; ++k) d = fmaf(p1[k], vv[k], d);
            bval += d;
        }

        // softmax over the 32 capsules (32-lane shuffle groups inside wave64)
        float m = bval;
#pragma unroll
        for (int off = 16; off > 0; off >>= 1)
            m = fmaxf(m, __shfl_xor(m, off, 32));
        float e = __expf(bval - m);
        float ssum = e;
#pragma unroll
        for (int off = 16; off > 0; off >>= 1)
            ssum += __shfl_xor(ssum, off, 32);
        float c = e / ssum;

#pragma unroll
        for (int k = 0; k < POSE; ++k) acc[k] = fmaf(c, vv[k], acc[k]);
        __syncthreads();
    }

    // reduce the 8 a_sub partials in LDS, write this block's chunk partial
    float* red = smem;
#pragma unroll
    for (int k = 0; k < POSE; ++k) red[a_sub * SLICE + bc * POSE + k] = acc[k];
    __syncthreads();

    for (int idx = t; idx < SLICE; idx += 256) {
        float s = 0.f;
#pragma unroll
        for (int asb = 0; asb < 8; ++asb) s += red[asb * SLICE + idx];
        s_out[((size_t)bt * CHUNKS + chunk) * SLICE + idx] = s;
    }
}

// final: reduce iter-2 chunk partials, squash, emit a_out (8192) ++ p (32768)
__global__ __launch_bounds__(512) void final_out(
    const float* __restrict__ s_part2,  // [bt][chunk][SLICE]
    float* __restrict__ out)
{
    const int bt = blockIdx.x;
    const int t  = threadIdx.x;        // t = bc*16 + pose
    const int pose = t & 15;

    __shared__ float sq[512];
    __shared__ float ns[16];

    float sv = 0.f;
#pragma unroll
    for (int c = 0; c < CHUNKS; ++c)
        sv += s_part2[((size_t)bt * CHUNKS + c) * SLICE + t];

    sq[t] = sv * sv;
    __syncthreads();
    if (t < 16) {
        float a = 0.f;
        for (int b2 = 0; b2 < BDIM; ++b2) a += sq[b2 * POSE + t];
        ns[t] = a;
    }
    __syncthreads();
    float n = ns[pose];
    float pv = sqrtf(n + EPSQ) / (1.f + n) * sv;

    out[8192 + bt * SLICE + t] = pv;
    sq[t] = pv * pv;
    __syncthreads();
    // a_out[bt][bc][p2] = sqrt(sum_p1 p[bc][p1][p2]^2)
    if (t < 128) {
        int b2 = t >> 2, p2 = t & 3;
        float a = 0.f;
#pragma unroll
        for (int p1 = 0; p1 < 4; ++p1) a += sq[b2 * POSE + p1 * 4 + p2];
        out[bt * 128 + b2 * 4 + p2] = sqrtf(a);
    }
}

extern "C" void kernel_launch(void* const* d_in, const int* in_sizes, int n_in,
                              void* d_out, int out_size, void* d_ws, size_t ws_size,
                              hipStream_t stream) {
    const float* v      = (const float*)d_in[1];   // (64,1152,32,4,4,1)
    const float* logits = (const float*)d_in[2];   // (1,1152,32,1,1,1)
    float* out = (float*)d_out;

    // workspace: s_part[3][BATCH][CHUNKS][SLICE] fp32 = 6 MB (no memset needed:
    // every element is written before it is read)
    float* s_part = (float*)d_ws;

    route_pass<0><<<dim3(BATCH * CHUNKS), dim3(256), 0, stream>>>(
        v, logits, s_part, s_part + 0 * SPART_ITER);
    route_pass<1><<<dim3(BATCH * CHUNKS), dim3(256), 0, stream>>>(
        v, logits, s_part, s_part + 1 * SPART_ITER);
    route_pass<2><<<dim3(BATCH * CHUNKS), dim3(256), 0, stream>>>(
        v, logits, s_part, s_part + 2 * SPART_ITER);
    final_out<<<dim3(BATCH), dim3(512), 0, stream>>>(
        s_part + 2 * SPART_ITER, out);
}